// Round 1
// baseline (1388.532 us; speedup 1.0000x reference)
//
#include <hip/hip_runtime.h>
#include <hip/hip_bf16.h>

// Problem constants (fixed-shape problem)
#define EDGES   640000
#define NNODES  50000
#define MDIM    128
#define DDIM    128
#define CDIM    256   // M+D
#define HDIM    64

#define XSTR    36    // padded LDS stride (floats) per edge chunk row (16B-aligned, 144B)

__device__ __forceinline__ void atomAddF(float* p, float v) {
    unsafeAtomicAdd(p, v);   // native global_atomic_add_f32 on gfx950
}

// K0: transpose W1 [64,256] -> W1t [256,64] so columns are contiguous for s_load streaming
__global__ void k0_prep(const float* __restrict__ w1, float* __restrict__ w1t) {
    int i = blockIdx.x * 256 + threadIdx.x;
    if (i < HDIM * CDIM) {
        int j = i >> 8;        // row of W1 (0..63)
        int k = i & 255;       // col of W1 (0..255)
        w1t[k * HDIM + j] = w1[i];
    }
}

// K1: per-edge attention MLP -> weights[e]; also accumulate sum_weights via atomics.
// Lane-per-edge: each lane owns one edge, holds h[64] in VGPRs.
// W1t columns stream through SGPRs (uniform loads); x chunks staged in LDS.
__global__ __launch_bounds__(256, 4) void k1_weights(
    const float* __restrict__ msgs,    // [E,128]
    const int*   __restrict__ tgt,     // [E]
    const float* __restrict__ feats,   // [N,128]
    const float* __restrict__ w1t,     // [256,64] transposed
    const float* __restrict__ b1,      // [64]
    const float* __restrict__ w2,      // [64]
    float*       __restrict__ weights, // [E] out
    float*       __restrict__ wsum)    // [N] accum
{
    __shared__ float xs[4][64 * XSTR];   // 36,864 B
    const int wv  = threadIdx.x >> 6;
    const int L   = threadIdx.x & 63;
    const long base = ((long)blockIdx.x * 4 + wv) * 64;  // first edge of this wave
    float* xb = xs[wv];

    float h[HDIM];
#pragma unroll
    for (int j = 0; j < HDIM; ++j) h[j] = 0.0f;

    const int g = L >> 3, sub = L & 7;

    for (int c = 0; c < 8; ++c) {             // 8 chunks of 32 concat-columns
        const bool isMsg = (c < 4);
        const int col0 = (isMsg ? c : (c - 4)) * 32;
        // stage 64 edges x 32 floats, coalesced: 8 lanes cover one edge-row chunk
#pragma unroll
        for (int r = 0; r < 8; ++r) {
            const int e = g + 8 * r;          // local edge 0..63
            const long ge = base + e;
            const float* src;
            if (isMsg) {
                src = msgs + ge * MDIM + col0;
            } else {
                const int t = tgt[ge];
                src = feats + (long)t * DDIM + col0;
            }
            float4 v = *(const float4*)(src + sub * 4);
            *(float4*)(xb + e * XSTR + sub * 4) = v;
        }
        __syncthreads();
        // compute: 32 k-steps, 64 FMAs each; W1 from scalar regs, x broadcastless (own lane)
        for (int k4 = 0; k4 < 8; ++k4) {
            const float4 xv = *(const float4*)(xb + L * XSTR + 4 * k4);
            const float* colw = w1t + (c * 32 + 4 * k4) * HDIM;
            const float xarr[4] = {xv.x, xv.y, xv.z, xv.w};
#pragma unroll
            for (int kk = 0; kk < 4; ++kk) {
                const float xk = xarr[kk];
#pragma unroll
                for (int j = 0; j < HDIM; ++j)
                    h[j] = fmaf(colw[kk * HDIM + j], xk, h[j]);
            }
        }
        __syncthreads();
    }

    // epilogue: bias + exact gelu + dot(W2) + sigmoid
    const long e = base + L;
    float raw = 0.0f;
#pragma unroll
    for (int j = 0; j < HDIM; ++j) {
        const float hj = h[j] + b1[j];
        const float gj = 0.5f * hj * (1.0f + erff(hj * 0.70710678118654752f));
        raw = fmaf(gj, w2[j], raw);
    }
    const float w = 1.0f / (1.0f + __expf(-raw));
    weights[e] = w;
    atomAddF(&wsum[tgt[e]], w);
}

// K2: weighted scatter of messages into agg (d_out) via fp32 atomics.
// One wave per edge-iteration; weights/tgt are wave-uniform (s_load).
__global__ void k2_scatter(const float* __restrict__ msgs,
                           const int*   __restrict__ tgt,
                           const float* __restrict__ wts,
                           float*       __restrict__ agg)
{
    const int L  = threadIdx.x & 63;
    const int wv = threadIdx.x >> 6;
    const long wid = (long)blockIdx.x * 4 + wv;
    const long nw  = (long)gridDim.x * 4;
    for (long e = wid; e < EDGES; e += nw) {
        const float w = wts[e];
        const int   t = tgt[e];
        const float2 m = *(const float2*)(msgs + e * MDIM + 2 * L);
        float* dst = agg + (long)t * MDIM + 2 * L;
        atomAddF(dst,     m.x * w);
        atomAddF(dst + 1, m.y * w);
    }
}

// K3: divide by (sum_weights + 1e-8), LayerNorm over 128 dims, scale/shift. In-place on d_out.
__global__ void k3_norm(float* __restrict__ agg,
                        const float* __restrict__ wsum,
                        const float* __restrict__ gamma,
                        const float* __restrict__ beta)
{
    const int L  = threadIdx.x & 63;
    const int wv = threadIdx.x >> 6;
    const int row = blockIdx.x * 4 + wv;
    if (row >= NNODES) return;
    const float inv = 1.0f / (wsum[row] + 1e-8f);
    float2 a = *(const float2*)(agg + (long)row * MDIM + 2 * L);
    a.x *= inv; a.y *= inv;
    float s1 = a.x + a.y;
    float s2 = a.x * a.x + a.y * a.y;
#pragma unroll
    for (int off = 32; off; off >>= 1) {
        s1 += __shfl_xor(s1, off, 64);
        s2 += __shfl_xor(s2, off, 64);
    }
    const float mu  = s1 * (1.0f / MDIM);
    const float var = s2 * (1.0f / MDIM) - mu * mu;
    const float rs  = rsqrtf(var + 1e-5f);
    const float2 gm = *(const float2*)(gamma + 2 * L);
    const float2 bt = *(const float2*)(beta + 2 * L);
    float2 o;
    o.x = (a.x - mu) * rs * gm.x + bt.x;
    o.y = (a.y - mu) * rs * gm.y + bt.y;
    *(float2*)(agg + (long)row * MDIM + 2 * L) = o;
}

extern "C" void kernel_launch(void* const* d_in, const int* in_sizes, int n_in,
                              void* d_out, int out_size, void* d_ws, size_t ws_size,
                              hipStream_t stream) {
    const float* msgs  = (const float*)d_in[0];
    const int*   tgt   = (const int*)d_in[1];
    const float* feats = (const float*)d_in[2];
    // d_in[3] = n_nodes scalar (unused; shapes fixed)
    const float* W1    = (const float*)d_in[4];
    const float* b1    = (const float*)d_in[5];
    const float* W2    = (const float*)d_in[6];
    const float* gamma = (const float*)d_in[7];
    const float* beta  = (const float*)d_in[8];
    float* out = (float*)d_out;

    char* ws = (char*)d_ws;
    float* wsum = (float*)ws;                        // 200,000 B
    float* w1t  = (float*)(ws + 256 * 1024);         // 64 KB
    float* wts  = (float*)(ws + 512 * 1024);         // 2.56 MB

    // zero accumulators (ws/out are poisoned before every timed call)
    hipMemsetAsync(out, 0, (size_t)NNODES * MDIM * sizeof(float), stream);
    hipMemsetAsync(wsum, 0, (size_t)NNODES * sizeof(float), stream);

    k0_prep<<<(HDIM * CDIM + 255) / 256, 256, 0, stream>>>(W1, w1t);
    k1_weights<<<EDGES / 256, 256, 0, stream>>>(msgs, tgt, feats, w1t, b1, W2, wts, wsum);
    k2_scatter<<<2560, 256, 0, stream>>>(msgs, tgt, wts, out);
    k3_norm<<<(NNODES + 3) / 4, 256, 0, stream>>>(out, wsum, gamma, beta);
}

// Round 2
// 885.355 us; speedup vs baseline: 1.5683x; 1.5683x over previous
//
#include <hip/hip_runtime.h>

#define EDGES   640000
#define NNODES  50000
#define MDIM    128
#define HDIM    64
#define XSTR    36    // padded LDS stride (floats)

// ---------------- K0: split+transpose W1 [64][256] -> w1mt[128][64], w1dt[128][64]
__global__ void k0_prep(const float* __restrict__ w1,
                        float* __restrict__ w1mt, float* __restrict__ w1dt) {
    int i = blockIdx.x * 256 + threadIdx.x;
    if (i < HDIM * 256) {
        int j = i >> 8, k = i & 255;
        float v = w1[i];
        if (k < 128) w1mt[k * HDIM + j] = v;
        else         w1dt[(k - 128) * HDIM + j] = v;
    }
}

// ---------------- KG: g[n][j] = b1[j] + sum_k feats[n][k] * W1d[j][k]   (lane-per-node)
__global__ __launch_bounds__(256, 4) void kg_nodes(
    const float* __restrict__ feats, const float* __restrict__ w1dt,
    const float* __restrict__ b1, float* __restrict__ g)
{
    __shared__ float xs[4][64 * XSTR];
    const int wv = threadIdx.x >> 6, L = threadIdx.x & 63;
    const long base = ((long)blockIdx.x * 4 + wv) * 64;
    float* xb = xs[wv];
    float h[HDIM];
#pragma unroll
    for (int j = 0; j < HDIM; ++j) h[j] = 0.0f;
    const int gq = L >> 3, sub = L & 7;
    for (int c = 0; c < 4; ++c) {
        const int col0 = c * 32;
#pragma unroll
        for (int r = 0; r < 8; ++r) {
            long row = base + gq + 8 * r;
            if (row > NNODES - 1) row = NNODES - 1;   // clamp tail block
            float4 v = *(const float4*)(feats + row * MDIM + col0 + sub * 4);
            *(float4*)(xb + (gq + 8 * r) * XSTR + sub * 4) = v;
        }
        __syncthreads();
        for (int k4 = 0; k4 < 8; ++k4) {
            const float4 xv = *(const float4*)(xb + L * XSTR + 4 * k4);
            const float* colw = w1dt + (c * 32 + 4 * k4) * HDIM;
            const float xa[4] = {xv.x, xv.y, xv.z, xv.w};
#pragma unroll
            for (int kk = 0; kk < 4; ++kk) {
                const float xk = xa[kk];
#pragma unroll
                for (int j = 0; j < HDIM; ++j)
                    h[j] = fmaf(colw[kk * HDIM + j], xk, h[j]);
            }
        }
        __syncthreads();
    }
    const long row = base + L;
    if (row < NNODES) {
        float* gp = g + row * HDIM;
#pragma unroll
        for (int j4 = 0; j4 < 16; ++j4) {
            float4 b4 = *(const float4*)(b1 + 4 * j4);
            float4 o;
            o.x = h[4 * j4 + 0] + b4.x; o.y = h[4 * j4 + 1] + b4.y;
            o.z = h[4 * j4 + 2] + b4.z; o.w = h[4 * j4 + 3] + b4.w;
            *(float4*)(gp + 4 * j4) = o;
        }
    }
}

// ---------------- K1: per-edge weights; h = W1m@msg, + g[tgt] in epilogue. Also histogram counts.
__global__ __launch_bounds__(256, 4) void k1_weights(
    const float* __restrict__ msgs, const int* __restrict__ tgt,
    const float* __restrict__ w1mt, const float* __restrict__ g,
    const float* __restrict__ w2, float* __restrict__ weights,
    int* __restrict__ counts)
{
    __shared__ float xs[4][64 * XSTR];
    const int wv = threadIdx.x >> 6, L = threadIdx.x & 63;
    const long base = ((long)blockIdx.x * 4 + wv) * 64;
    float* xb = xs[wv];
    float h[HDIM];
#pragma unroll
    for (int j = 0; j < HDIM; ++j) h[j] = 0.0f;
    const int gq = L >> 3, sub = L & 7;
    for (int c = 0; c < 4; ++c) {
        const int col0 = c * 32;
#pragma unroll
        for (int r = 0; r < 8; ++r) {
            const long ge = base + gq + 8 * r;
            float4 v = *(const float4*)(msgs + ge * MDIM + col0 + sub * 4);
            *(float4*)(xb + (gq + 8 * r) * XSTR + sub * 4) = v;
        }
        __syncthreads();
        for (int k4 = 0; k4 < 8; ++k4) {
            const float4 xv = *(const float4*)(xb + L * XSTR + 4 * k4);
            const float* colw = w1mt + (c * 32 + 4 * k4) * HDIM;
            const float xa[4] = {xv.x, xv.y, xv.z, xv.w};
#pragma unroll
            for (int kk = 0; kk < 4; ++kk) {
                const float xk = xa[kk];
#pragma unroll
                for (int j = 0; j < HDIM; ++j)
                    h[j] = fmaf(colw[kk * HDIM + j], xk, h[j]);
            }
        }
        __syncthreads();
    }
    // epilogue: + g[t][j] (includes b1), exact gelu, dot W2, sigmoid
    const long e = base + L;
    const int t = tgt[e];
    const float* gp = g + (long)t * HDIM;
    float raw = 0.0f;
#pragma unroll
    for (int j4 = 0; j4 < 16; ++j4) {
        const float4 gv = *(const float4*)(gp + 4 * j4);
        const float4 w4 = *(const float4*)(w2 + 4 * j4);
        const float ga[4] = {gv.x, gv.y, gv.z, gv.w};
        const float wa[4] = {w4.x, w4.y, w4.z, w4.w};
#pragma unroll
        for (int kk = 0; kk < 4; ++kk) {
            const float hj = h[4 * j4 + kk] + ga[kk];
            const float gel = 0.5f * hj * (1.0f + erff(hj * 0.70710678118654752f));
            raw = fmaf(gel, wa[kk], raw);
        }
    }
    const float w = 1.0f / (1.0f + __expf(-raw));
    weights[e] = w;
    atomicAdd(&counts[t], 1);
}

// ---------------- CSR build: local scan -> block-sum scan -> fixup, then index scatter
__global__ void kscan_local(const int* __restrict__ counts, int* __restrict__ offsets,
                            int* __restrict__ blocksums) {
    __shared__ int s[256];
    const int tid = threadIdx.x;
    const int i = blockIdx.x * 256 + tid;
    int v = (i < NNODES) ? counts[i] : 0;
    s[tid] = v;
    __syncthreads();
    for (int d = 1; d < 256; d <<= 1) {
        int t = (tid >= d) ? s[tid - d] : 0;
        __syncthreads();
        s[tid] += t;
        __syncthreads();
    }
    if (i < NNODES) offsets[i] = s[tid];          // local inclusive
    if (tid == 255) blocksums[blockIdx.x] = s[255];
}

__global__ void kscan_blk(int* __restrict__ blocksums, int nblk) {
    __shared__ int s[256];
    const int tid = threadIdx.x;
    int v = (tid < nblk) ? blocksums[tid] : 0;
    s[tid] = v;
    __syncthreads();
    for (int d = 1; d < 256; d <<= 1) {
        int t = (tid >= d) ? s[tid - d] : 0;
        __syncthreads();
        s[tid] += t;
        __syncthreads();
    }
    if (tid < nblk) blocksums[tid] = s[tid] - v;  // exclusive
}

__global__ void kscan_fix(int* __restrict__ offsets, const int* __restrict__ blocksums,
                          const int* __restrict__ counts, int* __restrict__ cursor) {
    const int i = blockIdx.x * 256 + threadIdx.x;
    if (i < NNODES) {
        const int incl = offsets[i] + blocksums[i >> 8];
        offsets[i] = incl;              // global inclusive
        cursor[i] = incl - counts[i];   // segment start
    }
}

__global__ void kscatter(const int* __restrict__ tgt, int* __restrict__ cursor,
                         int* __restrict__ eidx) {
    const int e = blockIdx.x * 256 + threadIdx.x;
    if (e < EDGES) {
        const int pos = atomicAdd(&cursor[tgt[e]], 1);
        eidx[pos] = e;
    }
}

// ---------------- K_AGG: wave-per-node gather of msg*w, + divide + LayerNorm, write out.
__global__ __launch_bounds__(256) void kagg(
    const float* __restrict__ msgs, const float* __restrict__ wts,
    const int* __restrict__ eidx, const int* __restrict__ offsets,
    const float* __restrict__ gamma, const float* __restrict__ beta,
    float* __restrict__ out)
{
    const int L = threadIdx.x & 63, wv = threadIdx.x >> 6;
    const int n = blockIdx.x * 4 + wv;
    if (n >= NNODES) return;
    const int end = offsets[n];
    const int beg = (n == 0) ? 0 : offsets[n - 1];
    float2 acc = {0.0f, 0.0f};
    float sw = 0.0f;
    for (int i = beg; i < end; ++i) {
        const int eid = eidx[i];
        const float w = wts[eid];
        const float2 m = *(const float2*)(msgs + (long)eid * MDIM + 2 * L);
        acc.x = fmaf(m.x, w, acc.x);
        acc.y = fmaf(m.y, w, acc.y);
        sw += w;
    }
    const float inv = 1.0f / (sw + 1e-8f);
    float2 a;
    a.x = acc.x * inv; a.y = acc.y * inv;
    float s1 = a.x + a.y;
    float s2 = a.x * a.x + a.y * a.y;
#pragma unroll
    for (int off = 32; off; off >>= 1) {
        s1 += __shfl_xor(s1, off, 64);
        s2 += __shfl_xor(s2, off, 64);
    }
    const float mu = s1 * (1.0f / MDIM);
    const float var = s2 * (1.0f / MDIM) - mu * mu;
    const float rs = rsqrtf(var + 1e-5f);
    const float2 gm = *(const float2*)(gamma + 2 * L);
    const float2 bt = *(const float2*)(beta + 2 * L);
    float2 o;
    o.x = (a.x - mu) * rs * gm.x + bt.x;
    o.y = (a.y - mu) * rs * gm.y + bt.y;
    *(float2*)(out + (long)n * MDIM + 2 * L) = o;
}

extern "C" void kernel_launch(void* const* d_in, const int* in_sizes, int n_in,
                              void* d_out, int out_size, void* d_ws, size_t ws_size,
                              hipStream_t stream) {
    const float* msgs  = (const float*)d_in[0];
    const int*   tgt   = (const int*)d_in[1];
    const float* feats = (const float*)d_in[2];
    const float* W1    = (const float*)d_in[4];
    const float* b1    = (const float*)d_in[5];
    const float* W2    = (const float*)d_in[6];
    const float* gamma = (const float*)d_in[7];
    const float* beta  = (const float*)d_in[8];
    float* out = (float*)d_out;

    char* ws = (char*)d_ws;
    float* w1mt    = (float*)(ws + 0);                 //  32 KB
    float* w1dt    = (float*)(ws + (32 << 10));        //  32 KB
    int*   counts  = (int*)  (ws + (64 << 10));        // 200 KB
    int*   offsets = (int*)  (ws + (320 << 10));       // 200 KB
    int*   cursor  = (int*)  (ws + (576 << 10));       // 200 KB
    int*   bsums   = (int*)  (ws + (832 << 10));       //   1 KB
    float* wts     = (float*)(ws + (1 << 20));         // 2.56 MB
    int*   eidx    = (int*)  (ws + (4 << 20));         // 2.56 MB
    float* g       = (float*)(ws + (8 << 20));         // 12.8 MB   (end ~20.8 MB)

    hipMemsetAsync(counts, 0, NNODES * sizeof(int), stream);

    k0_prep<<<64, 256, 0, stream>>>(W1, w1mt, w1dt);
    kg_nodes<<<(NNODES + 255) / 256, 256, 0, stream>>>(feats, w1dt, b1, g);
    k1_weights<<<EDGES / 256, 256, 0, stream>>>(msgs, tgt, w1mt, g, W2, wts, counts);
    const int nblk = (NNODES + 255) / 256;             // 196
    kscan_local<<<nblk, 256, 0, stream>>>(counts, offsets, bsums);
    kscan_blk<<<1, 256, 0, stream>>>(bsums, nblk);
    kscan_fix<<<nblk, 256, 0, stream>>>(offsets, bsums, counts, cursor);
    kscatter<<<(EDGES + 255) / 256, 256, 0, stream>>>(tgt, cursor, eidx);
    kagg<<<(NNODES + 3) / 4, 256, 0, stream>>>(msgs, wts, eidx, offsets, gamma, beta, out);
}

// Round 3
// 672.214 us; speedup vs baseline: 2.0656x; 1.3171x over previous
//
#include <hip/hip_runtime.h>
#include <hip/hip_bf16.h>

#define EDGES   640000
#define NNODES  50000
#define MDIM    128
#define HDIM    64
#define XSTR    36    // padded LDS stride (floats) for f32 staging kernels

typedef __attribute__((ext_vector_type(8))) short bshort8;  // 8 bf16 = 4 VGPRs
typedef __attribute__((ext_vector_type(4))) float f32x4;    // MFMA acc

__device__ __forceinline__ short f2bf(float f) {
    __hip_bfloat16 h = __float2bfloat16(f);
    return *reinterpret_cast<short*>(&h);
}

// ---------------- K0: pack W1 message-half into bf16 MFMA B-fragment layout (bpack),
//                  and W1 feature-half transposed f32 (w1dt) for kg_nodes.
// bpack[((kc*4+jt)*64 + lane)*8 + ii] = bf16( W1[j][k] ), j=jt*16+(lane&15),
//   k = kc*32 + (lane>>4)*8 + ii.   (B[k][n] frag layout: n=lane&15, k=quad*8+ii)
__global__ void k0_prep(const float* __restrict__ w1,
                        short* __restrict__ bpack, float* __restrict__ w1dt) {
    const int i = blockIdx.x * 256 + threadIdx.x;   // 0..16383
    if (i < 8192) {
        const int ii   = i & 7;
        const int lane = (i >> 3) & 63;
        const int jtkc = i >> 9;            // kc*4 + jt
        const int kc = jtkc >> 2, jt = jtkc & 3;
        const int j = jt * 16 + (lane & 15);
        const int k = kc * 32 + (lane >> 4) * 8 + ii;
        bpack[i] = f2bf(w1[j * 256 + k]);
    } else if (i < 16384) {
        const int t = i - 8192;             // w1dt[k][j] = W1[j][128+k]
        const int k = t >> 6, j = t & 63;
        w1dt[t] = w1[j * 256 + 128 + k];
    }
}

// ---------------- KG: g[n][j] = b1[j] + sum_k feats[n][k]*W1d[j][k]  (f32 FMA, lane-per-node)
__global__ __launch_bounds__(256, 4) void kg_nodes(
    const float* __restrict__ feats, const float* __restrict__ w1dt,
    const float* __restrict__ b1, float* __restrict__ g)
{
    __shared__ float xs[4][64 * XSTR];
    const int wv = threadIdx.x >> 6, L = threadIdx.x & 63;
    const long base = ((long)blockIdx.x * 4 + wv) * 64;
    float* xb = xs[wv];
    float h[HDIM];
#pragma unroll
    for (int j = 0; j < HDIM; ++j) h[j] = 0.0f;
    const int gq = L >> 3, sub = L & 7;
    for (int c = 0; c < 4; ++c) {
        const int col0 = c * 32;
#pragma unroll
        for (int r = 0; r < 8; ++r) {
            long row = base + gq + 8 * r;
            if (row > NNODES - 1) row = NNODES - 1;
            float4 v = *(const float4*)(feats + row * MDIM + col0 + sub * 4);
            *(float4*)(xb + (gq + 8 * r) * XSTR + sub * 4) = v;
        }
        __syncthreads();
        for (int k4 = 0; k4 < 8; ++k4) {
            const float4 xv = *(const float4*)(xb + L * XSTR + 4 * k4);
            const float* colw = w1dt + (c * 32 + 4 * k4) * HDIM;
            const float xa[4] = {xv.x, xv.y, xv.z, xv.w};
#pragma unroll
            for (int kk = 0; kk < 4; ++kk) {
                const float xk = xa[kk];
#pragma unroll
                for (int j = 0; j < HDIM; ++j)
                    h[j] = fmaf(colw[kk * HDIM + j], xk, h[j]);
            }
        }
        __syncthreads();
    }
    const long row = base + L;
    if (row < NNODES) {
        float* gp = g + row * HDIM;
#pragma unroll
        for (int j4 = 0; j4 < 16; ++j4) {
            float4 b4 = *(const float4*)(b1 + 4 * j4);
            float4 o;
            o.x = h[4 * j4 + 0] + b4.x; o.y = h[4 * j4 + 1] + b4.y;
            o.z = h[4 * j4 + 2] + b4.z; o.w = h[4 * j4 + 3] + b4.w;
            *(float4*)(gp + 4 * j4) = o;
        }
    }
}

// ---------------- K1: MFMA edge MLP. 16 edges/wave: H[16,64] = bf16(msgs)[16,128] @ W1m^T.
// Epilogue: +g[tgt], exact gelu, dot w2 (in-quad shfl reduce), sigmoid -> wts; histogram counts.
__global__ __launch_bounds__(256, 2) void k1_weights(
    const float* __restrict__ msgs, const int* __restrict__ tgt,
    const short* __restrict__ bpack, const float* __restrict__ g,
    const float* __restrict__ w2, float* __restrict__ weights,
    int* __restrict__ counts)
{
    __shared__ short lds[4][16 * 136];   // 16 edges x 128 bf16, +8 bf16 pad -> 4352 B/wave
    const int wv = threadIdx.x >> 6, L = threadIdx.x & 63;
    const long base = ((long)blockIdx.x * 4 + wv) * 16;
    short* xb = lds[wv];

    // B fragments: 16 x 16B per lane, L1/L2-resident
    const bshort8* bp = (const bshort8*)bpack;
    bshort8 bfrag[16];
#pragma unroll
    for (int i = 0; i < 16; ++i) bfrag[i] = bp[i * 64 + L];

    // stage 16 edges x 128 f32 -> bf16 LDS (2 edges = 1 KB per round, coalesced)
    const int se = L >> 5, k4 = L & 31;
#pragma unroll
    for (int r = 0; r < 8; ++r) {
        const int edge = 2 * r + se;
        const float4 v = *(const float4*)(msgs + (base + edge) * MDIM + k4 * 4);
        short4 s;
        s.x = f2bf(v.x); s.y = f2bf(v.y); s.z = f2bf(v.z); s.w = f2bf(v.w);
        *(short4*)(xb + edge * 136 + k4 * 4) = s;
    }
    __syncthreads();

    const int n = L & 15, quad = L >> 4;
    f32x4 acc[4];
#pragma unroll
    for (int jt = 0; jt < 4; ++jt) acc[jt] = (f32x4){0.f, 0.f, 0.f, 0.f};

#pragma unroll
    for (int kc = 0; kc < 4; ++kc) {
        const bshort8 a = *(const bshort8*)(xb + n * 136 + kc * 32 + quad * 8);
#pragma unroll
        for (int jt = 0; jt < 4; ++jt)
            acc[jt] = __builtin_amdgcn_mfma_f32_16x16x32_bf16(a, bfrag[kc * 4 + jt], acc[jt], 0, 0, 0);
    }

    // epilogue: lane holds h[edge=quad*4+r][j=jt*16+n], r=0..3
    float w2v[4];
#pragma unroll
    for (int jt = 0; jt < 4; ++jt) w2v[jt] = w2[jt * 16 + n];

#pragma unroll
    for (int r = 0; r < 4; ++r) {
        const long e = base + quad * 4 + r;
        const int t = tgt[e];
        const float* gp = g + (long)t * HDIM;
        float raw = 0.0f;
#pragma unroll
        for (int jt = 0; jt < 4; ++jt) {
            const float hj = acc[jt][r] + gp[jt * 16 + n];
            const float ge = 0.5f * hj * (1.0f + erff(hj * 0.70710678118654752f));
            raw = fmaf(ge, w2v[jt], raw);
        }
#pragma unroll
        for (int off = 1; off < 16; off <<= 1)
            raw += __shfl_xor(raw, off, 64);
        if (n == r) {
            weights[e] = 1.0f / (1.0f + __expf(-raw));
            atomicAdd(&counts[t], 1);
        }
    }
}

// ---------------- CSR build
__global__ void kscan_local(const int* __restrict__ counts, int* __restrict__ offsets,
                            int* __restrict__ blocksums) {
    __shared__ int s[256];
    const int tid = threadIdx.x;
    const int i = blockIdx.x * 256 + tid;
    int v = (i < NNODES) ? counts[i] : 0;
    s[tid] = v;
    __syncthreads();
    for (int d = 1; d < 256; d <<= 1) {
        int t = (tid >= d) ? s[tid - d] : 0;
        __syncthreads();
        s[tid] += t;
        __syncthreads();
    }
    if (i < NNODES) offsets[i] = s[tid];
    if (tid == 255) blocksums[blockIdx.x] = s[255];
}

__global__ void kscan_blk(int* __restrict__ blocksums, int nblk) {
    __shared__ int s[256];
    const int tid = threadIdx.x;
    int v = (tid < nblk) ? blocksums[tid] : 0;
    s[tid] = v;
    __syncthreads();
    for (int d = 1; d < 256; d <<= 1) {
        int t = (tid >= d) ? s[tid - d] : 0;
        __syncthreads();
        s[tid] += t;
        __syncthreads();
    }
    if (tid < nblk) blocksums[tid] = s[tid] - v;
}

__global__ void kscan_fix(int* __restrict__ offsets, const int* __restrict__ blocksums,
                          const int* __restrict__ counts, int* __restrict__ cursor) {
    const int i = blockIdx.x * 256 + threadIdx.x;
    if (i < NNODES) {
        const int incl = offsets[i] + blocksums[i >> 8];
        offsets[i] = incl;
        cursor[i] = incl - counts[i];
    }
}

__global__ void kscatter(const int* __restrict__ tgt, int* __restrict__ cursor,
                         int* __restrict__ eidx) {
    const int e = blockIdx.x * 256 + threadIdx.x;
    if (e < EDGES) {
        const int pos = atomicAdd(&cursor[tgt[e]], 1);
        eidx[pos] = e;
    }
}

// ---------------- K_AGG: wave-per-node; lane-parallel edge-meta load + shfl broadcast,
// independent msgs loads; fused divide + LayerNorm.
__global__ __launch_bounds__(256) void kagg(
    const float* __restrict__ msgs, const float* __restrict__ wts,
    const int* __restrict__ eidx, const int* __restrict__ offsets,
    const float* __restrict__ gamma, const float* __restrict__ beta,
    float* __restrict__ out)
{
    const int L = threadIdx.x & 63, wv = threadIdx.x >> 6;
    const int node = blockIdx.x * 4 + wv;
    if (node >= NNODES) return;
    const int end = offsets[node];
    const int beg = (node == 0) ? 0 : offsets[node - 1];
    float2 acc = {0.0f, 0.0f};
    float swl = 0.0f;
    for (int b = beg; b < end; b += 64) {
        int m = end - b; if (m > 64) m = 64;
        int eid = 0; float w = 0.0f;
        if (L < m) { eid = eidx[b + L]; w = wts[eid]; }
        swl += w;
        for (int i = 0; i < m; ++i) {
            const int e2 = __shfl(eid, i, 64);
            const float wi = __shfl(w, i, 64);
            const float2 mv = *(const float2*)(msgs + (long)e2 * MDIM + 2 * L);
            acc.x = fmaf(mv.x, wi, acc.x);
            acc.y = fmaf(mv.y, wi, acc.y);
        }
    }
    float s1 = acc.x + acc.y;
    float s2 = acc.x * acc.x + acc.y * acc.y;
#pragma unroll
    for (int off = 32; off; off >>= 1) {
        s1 += __shfl_xor(s1, off, 64);
        s2 += __shfl_xor(s2, off, 64);
        swl += __shfl_xor(swl, off, 64);
    }
    const float inv = 1.0f / (swl + 1e-8f);
    float2 a;
    a.x = acc.x * inv; a.y = acc.y * inv;
    const float mu = s1 * inv * (1.0f / MDIM);
    const float var = s2 * inv * inv * (1.0f / MDIM) - mu * mu;
    const float rs = rsqrtf(var + 1e-5f);
    const float2 gm = *(const float2*)(gamma + 2 * L);
    const float2 bt = *(const float2*)(beta + 2 * L);
    float2 o;
    o.x = (a.x - mu) * rs * gm.x + bt.x;
    o.y = (a.y - mu) * rs * gm.y + bt.y;
    *(float2*)(out + (long)node * MDIM + 2 * L) = o;
}

extern "C" void kernel_launch(void* const* d_in, const int* in_sizes, int n_in,
                              void* d_out, int out_size, void* d_ws, size_t ws_size,
                              hipStream_t stream) {
    const float* msgs  = (const float*)d_in[0];
    const int*   tgt   = (const int*)d_in[1];
    const float* feats = (const float*)d_in[2];
    const float* W1    = (const float*)d_in[4];
    const float* b1    = (const float*)d_in[5];
    const float* W2    = (const float*)d_in[6];
    const float* gamma = (const float*)d_in[7];
    const float* beta  = (const float*)d_in[8];
    float* out = (float*)d_out;

    char* ws = (char*)d_ws;
    short* bpack   = (short*)(ws + 0);                 //  16 KB
    float* w1dt    = (float*)(ws + (32 << 10));        //  32 KB
    int*   counts  = (int*)  (ws + (64 << 10));        // 200 KB
    int*   offsets = (int*)  (ws + (320 << 10));       // 200 KB
    int*   cursor  = (int*)  (ws + (576 << 10));       // 200 KB
    int*   bsums   = (int*)  (ws + (832 << 10));       //   1 KB
    float* wts     = (float*)(ws + (1 << 20));         // 2.56 MB
    int*   eidx    = (int*)  (ws + (4 << 20));         // 2.56 MB
    float* g       = (float*)(ws + (8 << 20));         // 12.8 MB

    hipMemsetAsync(counts, 0, NNODES * sizeof(int), stream);

    k0_prep<<<64, 256, 0, stream>>>(W1, bpack, w1dt);
    kg_nodes<<<(NNODES + 255) / 256, 256, 0, stream>>>(feats, w1dt, b1, g);
    k1_weights<<<EDGES / 64, 256, 0, stream>>>(msgs, tgt, bpack, g, W2, wts, counts);
    const int nblk = (NNODES + 255) / 256;
    kscan_local<<<nblk, 256, 0, stream>>>(counts, offsets, bsums);
    kscan_blk<<<1, 256, 0, stream>>>(bsums, nblk);
    kscan_fix<<<nblk, 256, 0, stream>>>(offsets, bsums, counts, cursor);
    kscatter<<<(EDGES + 255) / 256, 256, 0, stream>>>(tgt, cursor, eidx);
    kagg<<<(NNODES + 3) / 4, 256, 0, stream>>>(msgs, wts, eidx, offsets, gamma, beta, out);
}